// Round 1
// baseline (1446.808 us; speedup 1.0000x reference)
//
#include <hip/hip_runtime.h>
#include <math.h>

// ---------------------------------------------------------------------------
// Problem constants (B=8, S=1024, D=1024, N=1024, C=32, K=4, H=16, dh=64)
// ---------------------------------------------------------------------------
#define BB   8
#define SS   1024
#define DD   1024
#define NN_  1024
#define HH   16
#define DH   64

typedef __bf16 bf16x8 __attribute__((ext_vector_type(8)));
typedef float  f32x4  __attribute__((ext_vector_type(4)));

#define MFMA16(a, b, c) __builtin_amdgcn_mfma_f32_16x16x32_bf16(a, b, c, 0, 0, 0)

#define GLOAD_LDS16(GP, LP)                                                  \
    __builtin_amdgcn_global_load_lds(                                        \
        (const __attribute__((address_space(1))) void*)(GP),                 \
        (__attribute__((address_space(3))) void*)(LP), 16, 0, 0)

// RNE float->bf16 and back
__device__ __forceinline__ unsigned short f2bf(float f) {
    unsigned u = __float_as_uint(f);
    u += 0x7FFFu + ((u >> 16) & 1u);
    return (unsigned short)(u >> 16);
}
__device__ __forceinline__ float bf2f(unsigned short h) {
    return __uint_as_float((unsigned)h << 16);
}
__device__ __forceinline__ void split2(float f, unsigned short& h, unsigned short& l) {
    h = f2bf(f);
    l = f2bf(f - bf2f(h));          // residual is exact in f32
}

// LDS byte-address swizzle (involution): XOR bits 4-5 with bits 7-8.
// Spreads stride-64B row reads uniformly across the 8 16B-slots per 128B.
__device__ __forceinline__ int swzb(int x) { return x ^ (((x >> 7) & 3) << 4); }

// ---------------------------------------------------------------------------
// build_W -> hi/lo bf16 split output.
// out[b,n,d] = sum_k w[b,k]*inner[b,k,n]*table[idx[b,k],n,d]
// grid (N, B), block 256. Each thread: one float4 of the D=1024 row.
// ---------------------------------------------------------------------------
__global__ __launch_bounds__(256) void build_W_bf(
    const float* __restrict__ table, const int* __restrict__ idx,
    const float* __restrict__ w, const float* __restrict__ inner,
    unsigned short* __restrict__ outh, unsigned short* __restrict__ outl)
{
    const int n = blockIdx.x;
    const int b = blockIdx.y;
    const int t = threadIdx.x;

    const float c0 = w[b*4+0] * inner[((size_t)(b*4+0))*NN_ + n];
    const float c1 = w[b*4+1] * inner[((size_t)(b*4+1))*NN_ + n];
    const float c2 = w[b*4+2] * inner[((size_t)(b*4+2))*NN_ + n];
    const float c3 = w[b*4+3] * inner[((size_t)(b*4+3))*NN_ + n];

    const float4* r0 = (const float4*)(table + ((size_t)idx[b*4+0]*NN_ + n)*DD);
    const float4* r1 = (const float4*)(table + ((size_t)idx[b*4+1]*NN_ + n)*DD);
    const float4* r2 = (const float4*)(table + ((size_t)idx[b*4+2]*NN_ + n)*DD);
    const float4* r3 = (const float4*)(table + ((size_t)idx[b*4+3]*NN_ + n)*DD);

    float4 v0 = r0[t], v1 = r1[t], v2 = r2[t], v3 = r3[t];
    float4 o;
    o.x = c0*v0.x + c1*v1.x + c2*v2.x + c3*v3.x;
    o.y = c0*v0.y + c1*v1.y + c2*v2.y + c3*v3.y;
    o.z = c0*v0.z + c1*v1.z + c2*v2.z + c3*v3.z;
    o.w = c0*v0.w + c1*v1.w + c2*v2.w + c3*v3.w;

    ushort4 h, l;
    split2(o.x, h.x, l.x); split2(o.y, h.y, l.y);
    split2(o.z, h.z, l.z); split2(o.w, h.w, l.w);
    const size_t off = ((size_t)b*NN_ + n)*DD + (size_t)t*4;
    *(ushort4*)&outh[off] = h;
    *(ushort4*)&outl[off] = l;
}

// ---------------------------------------------------------------------------
// f32 -> bf16 hi/lo split, vectorized. n4 = total elements / 4.
// ---------------------------------------------------------------------------
__global__ __launch_bounds__(256) void convert_split(
    const float* __restrict__ in, unsigned short* __restrict__ oh,
    unsigned short* __restrict__ ol, int n4)
{
    const int i = blockIdx.x * 256 + threadIdx.x;
    if (i >= n4) return;
    float4 v = ((const float4*)in)[i];
    ushort4 h, l;
    split2(v.x, h.x, l.x); split2(v.y, h.y, l.y);
    split2(v.z, h.z, l.z); split2(v.w, h.w, l.w);
    ((ushort4*)oh)[i] = h;
    ((ushort4*)ol)[i] = l;
}

// ---------------------------------------------------------------------------
// Batched ushort transpose: src[b][n][d] -> dst[b][d][n]  (1024x1024 per b)
// grid (D/64, N/64, B), block 256. 64x64 tile via LDS.
// ---------------------------------------------------------------------------
__global__ __launch_bounds__(256) void transpose_u16(
    const unsigned short* __restrict__ src, unsigned short* __restrict__ dst)
{
    __shared__ __align__(16) unsigned short tile[64][72];
    const int d0 = blockIdx.x * 64;
    const int n0 = blockIdx.y * 64;
    const size_t B0 = (size_t)blockIdx.z * NN_ * DD;
    const int t = threadIdx.x;

    #pragma unroll
    for (int it = 0; it < 2; ++it) {
        const int idx = t + it * 256;          // 0..511
        const int r = idx >> 3;
        const int c = (idx & 7) * 8;
        *(uint4*)&tile[r][c] =
            *(const uint4*)&src[B0 + (size_t)(n0 + r)*DD + d0 + c];
    }
    __syncthreads();

    const int dr  = t >> 2;
    const int seg = (t & 3) * 16;
    unsigned v[8];
    #pragma unroll
    for (int u = 0; u < 8; ++u)
        v[u] = (unsigned)tile[seg + 2*u][dr] | ((unsigned)tile[seg + 2*u + 1][dr] << 16);
    uint4 a = make_uint4(v[0], v[1], v[2], v[3]);
    uint4 b = make_uint4(v[4], v[5], v[6], v[7]);
    unsigned short* drow = &dst[B0 + (size_t)(d0 + dr)*DD + n0 + seg];
    *(uint4*)&drow[0] = a;
    *(uint4*)&drow[8] = b;
}

// ---------------------------------------------------------------------------
// bf16x3 split-precision MFMA GEMM, NT layout:
//   C[m,n] = sum_k (Ah+Al)[m,k] * (Bh+Bl)[n,k]   (Al*Bl dropped, ~2^-16 rel)
// A*: [M][K] bf16 row-major, B*: [N][K] bf16 row-major. Batched via blockIdx.z.
// 128x128 tile, BK=32, 256 threads = 4 waves in 2x2; 64x64 per wave as 4x4
// frags of 16x16x32 MFMA. Staging: global_load_lds dwordx4, linear LDS dest,
// source pre-swizzled + swizzled ds_read (rule #21). mode 0: f32 C out;
// mode 1: hi/lo bf16 out (for chained GEMM inputs).
// ---------------------------------------------------------------------------
__global__ __launch_bounds__(256) void gemm_mfma_nt(
    const unsigned short* __restrict__ Ah, const unsigned short* __restrict__ Al,
    const unsigned short* __restrict__ Bh, const unsigned short* __restrict__ Bl,
    float* __restrict__ C, unsigned short* __restrict__ Ch, unsigned short* __restrict__ Cl,
    int M, int N, int K,
    long long sA, long long sB, long long sC, int mode)
{
    __shared__ __align__(16) unsigned short sAh[4096], sAl[4096], sBh[4096], sBl[4096];

    const int bz = blockIdx.z;
    const int n0 = blockIdx.x * 128;
    const int m0 = blockIdx.y * 128;
    const int t    = threadIdx.x;
    const int lane = t & 63;
    const int w    = t >> 6;
    const int lr   = lane >> 4;     // 0..3  (k-group / row-quad select)
    const int lc   = lane & 15;     // 0..15
    const int wm   = (w >> 1) * 64;
    const int wn   = (w & 1) * 64;

    const unsigned short* gAh = Ah + (size_t)bz * sA + (size_t)m0 * K;
    const unsigned short* gAl = Al + (size_t)bz * sA + (size_t)m0 * K;
    const unsigned short* gBh = Bh + (size_t)bz * sB + (size_t)n0 * K;
    const unsigned short* gBl = Bl + (size_t)bz * sB + (size_t)n0 * K;

    // Staging geometry: per wave, 2 chunks x 1KB per matrix. LDS dest is the
    // wave-uniform chunk base (+lane*16 by HW); global source address carries
    // the inverse swizzle so swizzled reads see logical [row][k] layout.
    int    ldsU[2];
    size_t gOff[2];
    #pragma unroll
    for (int j = 0; j < 2; ++j) {
        const int Ld = (w * 2 + j) * 1024 + lane * 16;   // linear dest byte
        const int Lg = swzb(Ld);                          // logical source byte
        ldsU[j] = ((w * 2 + j) * 1024) >> 1;              // uniform, ushort idx
        gOff[j] = (size_t)(Lg >> 6) * K + ((Lg & 63) >> 1);
    }

    // Fragment read offsets (swizzled), ushort index.
    // a-frag (m-block i): lane -> A[row = wm+16i+lc][k = 8*lr + 0..7]
    int aU[4], bU[4];
    #pragma unroll
    for (int i = 0; i < 4; ++i) {
        const int ra = wm + i * 16 + lc;
        aU[i] = swzb((ra << 6) | (lr << 4)) >> 1;
        const int rb = wn + i * 16 + lc;
        bU[i] = swzb((rb << 6) | (lr << 4)) >> 1;
    }

    f32x4 acc[4][4];
    #pragma unroll
    for (int i = 0; i < 4; ++i)
        #pragma unroll
        for (int j = 0; j < 4; ++j)
            acc[i][j] = (f32x4){0.f, 0.f, 0.f, 0.f};

    for (int k0 = 0; k0 < K; k0 += 32) {
        __syncthreads();                     // prev tile's frag reads done
        #pragma unroll
        for (int j = 0; j < 2; ++j) {
            const size_t go = gOff[j] + k0;
            GLOAD_LDS16(gAh + go, &sAh[ldsU[j]]);
            GLOAD_LDS16(gAl + go, &sAl[ldsU[j]]);
            GLOAD_LDS16(gBh + go, &sBh[ldsU[j]]);
            GLOAD_LDS16(gBl + go, &sBl[ldsU[j]]);
        }
        __syncthreads();                     // staging landed (vmcnt drained)

        bf16x8 ah[4], al[4], bh[4], bl[4];
        #pragma unroll
        for (int i = 0; i < 4; ++i) {
            ah[i] = *(const bf16x8*)&sAh[aU[i]];
            al[i] = *(const bf16x8*)&sAl[aU[i]];
            bh[i] = *(const bf16x8*)&sBh[bU[i]];
            bl[i] = *(const bf16x8*)&sBl[bU[i]];
        }
        #pragma unroll
        for (int i = 0; i < 4; ++i)
            #pragma unroll
            for (int j = 0; j < 4; ++j) {
                acc[i][j] = MFMA16(ah[i], bh[j], acc[i][j]);
                acc[i][j] = MFMA16(ah[i], bl[j], acc[i][j]);
                acc[i][j] = MFMA16(al[i], bh[j], acc[i][j]);
            }
    }

    // Epilogue. C/D layout: col = lane&15, row = 4*(lane>>4) + reg  [m89].
    const int gr0 = m0 + wm + lr * 4;
    const int gc0 = n0 + wn + lc;
    if (mode == 0) {
        float* Cb = C + (size_t)bz * sC;
        #pragma unroll
        for (int i = 0; i < 4; ++i)
            #pragma unroll
            for (int r = 0; r < 4; ++r) {
                const size_t ro = (size_t)(gr0 + i * 16 + r) * N;
                #pragma unroll
                for (int j = 0; j < 4; ++j)
                    Cb[ro + gc0 + j * 16] = acc[i][j][r];
            }
    } else {
        unsigned short* ChB = Ch + (size_t)bz * sC;
        unsigned short* ClB = Cl + (size_t)bz * sC;
        #pragma unroll
        for (int i = 0; i < 4; ++i)
            #pragma unroll
            for (int r = 0; r < 4; ++r) {
                const size_t ro = (size_t)(gr0 + i * 16 + r) * N;
                #pragma unroll
                for (int j = 0; j < 4; ++j) {
                    unsigned short h, l;
                    split2(acc[i][j][r], h, l);
                    ChB[ro + gc0 + j * 16] = h;
                    ClB[ro + gc0 + j * 16] = l;
                }
            }
    }
}

// ---------------------------------------------------------------------------
// Causal flash attention, register-blocked f32 (unchanged from prior best).
// grid (S/64, B*H), block 256.
// ---------------------------------------------------------------------------
#define APAD 68

__global__ __launch_bounds__(256) void attn_kernel(
    const float* __restrict__ Qg, const float* __restrict__ Kg,
    const float* __restrict__ Vg, float* __restrict__ Og)
{
    __shared__ float Qt[64][APAD];
    __shared__ float Kt[64][APAD];
    __shared__ float Vs[64][APAD];
    __shared__ float Pt[64][APAD];

    const int qt = blockIdx.x;
    const int bh = blockIdx.y;
    const int b  = bh / HH;
    const int h  = bh % HH;
    const int t  = threadIdx.x;
    const int tx = t & 15;
    const int ty = t >> 4;
    const int ty4 = ty * 4;
    const int tx4 = tx * 4;
    const size_t base = ((size_t)b * SS) * DD + (size_t)h * DH;
    const int q0 = qt * 64;

    #pragma unroll
    for (int u = 0; u < 4; ++u) {
        int e = t * 4 + u * 1024;
        int row = e >> 6, col = e & 63;
        float4 qv = *(const float4*)(Qg + base + (size_t)(q0 + row) * DD + col);
        Qt[col+0][row] = qv.x; Qt[col+1][row] = qv.y;
        Qt[col+2][row] = qv.z; Qt[col+3][row] = qv.w;
    }

    float o[4][4];
    float m_[4], l_[4];
    #pragma unroll
    for (int i = 0; i < 4; ++i) {
        m_[i] = -INFINITY; l_[i] = 0.f;
        #pragma unroll
        for (int j = 0; j < 4; ++j) o[i][j] = 0.f;
    }

    for (int kt = 0; kt <= qt; ++kt) {
        __syncthreads();
        #pragma unroll
        for (int u = 0; u < 4; ++u) {
            int e = t * 4 + u * 1024;
            int row = e >> 6, col = e & 63;
            float4 kv = *(const float4*)(Kg + base + (size_t)(kt*64 + row) * DD + col);
            Kt[col+0][row] = kv.x; Kt[col+1][row] = kv.y;
            Kt[col+2][row] = kv.z; Kt[col+3][row] = kv.w;
            float4 vv = *(const float4*)(Vg + base + (size_t)(kt*64 + row) * DD + col);
            *(float4*)&Vs[row][col] = vv;
        }
        __syncthreads();

        float s[4][4];
        #pragma unroll
        for (int i = 0; i < 4; ++i)
            #pragma unroll
            for (int j = 0; j < 4; ++j) s[i][j] = 0.f;

        #pragma unroll 4
        for (int kk = 0; kk < 64; ++kk) {
            float4 a = *(const float4*)&Qt[kk][ty4];
            float4 bv = *(const float4*)&Kt[kk][tx4];
            const float ar[4] = {a.x, a.y, a.z, a.w};
            const float br[4] = {bv.x, bv.y, bv.z, bv.w};
            #pragma unroll
            for (int i = 0; i < 4; ++i)
                #pragma unroll
                for (int j = 0; j < 4; ++j)
                    s[i][j] += ar[i] * br[j];
        }

        const int colbase = kt * 64 + tx4;
        const int rowbase = q0 + ty4;
        #pragma unroll
        for (int i = 0; i < 4; ++i) {
            float rmax = -INFINITY;
            #pragma unroll
            for (int j = 0; j < 4; ++j) {
                float sv = s[i][j] * 0.125f;
                if (colbase + j > rowbase + i) sv = -INFINITY;
                s[i][j] = sv;
                rmax = fmaxf(rmax, sv);
            }
            #pragma unroll
            for (int off = 1; off <= 8; off <<= 1)
                rmax = fmaxf(rmax, __shfl_xor(rmax, off, 64));
            const float mnew = fmaxf(m_[i], rmax);
            const float alpha = __expf(m_[i] - mnew);
            float rsum = 0.f;
            #pragma unroll
            for (int j = 0; j < 4; ++j) {
                float p = __expf(s[i][j] - mnew);
                s[i][j] = p;
                rsum += p;
            }
            #pragma unroll
            for (int off = 1; off <= 8; off <<= 1)
                rsum += __shfl_xor(rsum, off, 64);
            l_[i] = l_[i] * alpha + rsum;
            m_[i] = mnew;
            #pragma unroll
            for (int j = 0; j < 4; ++j) o[i][j] *= alpha;
        }

        #pragma unroll
        for (int j = 0; j < 4; ++j)
            #pragma unroll
            for (int i = 0; i < 4; ++i)
                Pt[tx4 + j][ty4 + i] = s[i][j];
        __syncthreads();

        #pragma unroll 4
        for (int kk = 0; kk < 64; ++kk) {
            float4 a = *(const float4*)&Pt[kk][ty4];
            float4 bv = *(const float4*)&Vs[kk][tx4];
            const float ar[4] = {a.x, a.y, a.z, a.w};
            const float br[4] = {bv.x, bv.y, bv.z, bv.w};
            #pragma unroll
            for (int i = 0; i < 4; ++i)
                #pragma unroll
                for (int j = 0; j < 4; ++j)
                    o[i][j] += ar[i] * br[j];
        }
    }

    #pragma unroll
    for (int i = 0; i < 4; ++i) {
        const float inv = 1.f / l_[i];
        float4 r;
        r.x = o[i][0] * inv; r.y = o[i][1] * inv;
        r.z = o[i][2] * inv; r.w = o[i][3] * inv;
        *(float4*)(Og + base + (size_t)(q0 + ty4 + i) * DD + tx4) = r;
    }
}

// ---------------------------------------------------------------------------
// Launch. Workspace: 6 x 32MB = 192MB (same budget as before), recycled:
//  buf0: W hi/lo (all 5 builds)            -> later Ab hi/lo
//  buf1: W^T hi/lo (3 NN gemms)            -> later W_O hi/lo
//  buf2: x hi/lo                           -> later Q (f32)
//  buf3: h_r hi/lo                         -> later V (f32)
//  buf4: h_v hi/lo                         -> later Ab (f32)
//  buf5: K (f32)
// ---------------------------------------------------------------------------
extern "C" void kernel_launch(void* const* d_in, const int* in_sizes, int n_in,
                              void* d_out, int out_size, void* d_ws, size_t ws_size,
                              hipStream_t stream)
{
    const float* x      = (const float*)d_in[0];
    const float* feat_r = (const float*)d_in[1];
    const float* feat_v = (const float*)d_in[2];
    const float* rel    = (const float*)d_in[3];
    const float* val    = (const float*)d_in[4];
    const float* W_O    = (const float*)d_in[5];
    const int*   idx_r  = (const int*)d_in[6];
    const float* w_r    = (const float*)d_in[7];
    const float* in_r   = (const float*)d_in[8];
    const int*   idx_v  = (const int*)d_in[9];
    const float* w_v    = (const float*)d_in[10];
    const float* in_v   = (const float*)d_in[11];
    const int*   idx_q  = (const int*)d_in[12];
    const float* w_q    = (const float*)d_in[13];
    const float* in_q   = (const float*)d_in[14];
    const int*   idx_k  = (const int*)d_in[15];
    const float* w_k    = (const float*)d_in[16];
    const float* in_k   = (const float*)d_in[17];
    const int*   idx_va = (const int*)d_in[18];
    const float* w_va   = (const float*)d_in[19];
    const float* in_va  = (const float*)d_in[20];

    char* base = (char*)d_ws;
    const size_t BUFB = (size_t)32 * 1024 * 1024;       // bytes per buffer
    const size_t HM   = (size_t)8 * 1024 * 1024;        // 8M ushorts = 16MB

    unsigned short* Wh  = (unsigned short*)(base + 0*BUFB);
    unsigned short* Wl  = Wh + HM;
    unsigned short* Th  = (unsigned short*)(base + 1*BUFB);
    unsigned short* Tl  = Th + HM;
    unsigned short* Xh  = (unsigned short*)(base + 2*BUFB);
    unsigned short* Xl  = Xh + HM;
    float*          Qb  = (float*)(base + 2*BUFB);      // after x dead
    unsigned short* Hrh = (unsigned short*)(base + 3*BUFB);
    unsigned short* Hrl = Hrh + HM;
    float*          Vb  = (float*)(base + 3*BUFB);      // after h_r dead
    unsigned short* Hvh = (unsigned short*)(base + 4*BUFB);
    unsigned short* Hvl = Hvh + HM;
    float*          Ab  = (float*)(base + 4*BUFB);      // after h_v dead
    float*          Kb  = (float*)(base + 5*BUFB);
    unsigned short* Abh = Wh;                           // buf0 reuse
    unsigned short* Abl = Wl;
    unsigned short* Woh = Th;                           // buf1 reuse
    unsigned short* Wol = Tl;

    const dim3 blk(256);
    const dim3 gBuild(NN_, BB);
    const dim3 gGemmB(8, 8, BB);                        // 1024^3 batched, 128^2 tiles
    const dim3 gTr(16, 16, BB);
    const long long sM = (long long)SS * DD;            // 1M elements

    // x -> hi/lo
    convert_split<<<8192, blk, 0, stream>>>(x, Xh, Xl, 2*1024*1024);

    // h_r = x @ W_r^T  (bf16 hi/lo out)
    build_W_bf<<<gBuild, blk, 0, stream>>>(feat_r, idx_r, w_r, in_r, Wh, Wl);
    gemm_mfma_nt<<<gGemmB, blk, 0, stream>>>(Xh, Xl, Wh, Wl, nullptr, Hrh, Hrl,
                                             SS, NN_, DD, sM, sM, sM, 1);
    // h_v = x @ W_v^T
    build_W_bf<<<gBuild, blk, 0, stream>>>(feat_v, idx_v, w_v, in_v, Wh, Wl);
    gemm_mfma_nt<<<gGemmB, blk, 0, stream>>>(Xh, Xl, Wh, Wl, nullptr, Hvh, Hvl,
                                             SS, NN_, DD, sM, sM, sM, 1);
    // Q = h_r @ W_rel_Q   (transpose W -> NT form; f32 out into old x buffer)
    build_W_bf<<<gBuild, blk, 0, stream>>>(rel, idx_q, w_q, in_q, Wh, Wl);
    transpose_u16<<<gTr, blk, 0, stream>>>(Wh, Th);
    transpose_u16<<<gTr, blk, 0, stream>>>(Wl, Tl);
    gemm_mfma_nt<<<gGemmB, blk, 0, stream>>>(Hrh, Hrl, Th, Tl, Qb, nullptr, nullptr,
                                             SS, DD, NN_, sM, sM, sM, 0);
    // K = h_r @ W_rel_K
    build_W_bf<<<gBuild, blk, 0, stream>>>(rel, idx_k, w_k, in_k, Wh, Wl);
    transpose_u16<<<gTr, blk, 0, stream>>>(Wh, Th);
    transpose_u16<<<gTr, blk, 0, stream>>>(Wl, Tl);
    gemm_mfma_nt<<<gGemmB, blk, 0, stream>>>(Hrh, Hrl, Th, Tl, Kb, nullptr, nullptr,
                                             SS, DD, NN_, sM, sM, sM, 0);
    // V = h_v @ W_val  (into old h_r buffer)
    build_W_bf<<<gBuild, blk, 0, stream>>>(val, idx_va, w_va, in_va, Wh, Wl);
    transpose_u16<<<gTr, blk, 0, stream>>>(Wh, Th);
    transpose_u16<<<gTr, blk, 0, stream>>>(Wl, Tl);
    gemm_mfma_nt<<<gGemmB, blk, 0, stream>>>(Hvh, Hvl, Th, Tl, Vb, nullptr, nullptr,
                                             SS, DD, NN_, sM, sM, sM, 0);

    // attention (f32) -> Ab (old h_v buffer)
    attn_kernel<<<dim3(SS/64, BB*HH), blk, 0, stream>>>(Qb, Kb, Vb, Ab);

    // out = Ab @ W_O^T  (M = 8192, single batch)
    convert_split<<<8192, blk, 0, stream>>>(Ab, Abh, Abl, 2*1024*1024);
    convert_split<<<1024, blk, 0, stream>>>(W_O, Woh, Wol, 256*1024);
    gemm_mfma_nt<<<dim3(8, 64, 1), blk, 0, stream>>>(Abh, Abl, Woh, Wol,
                                                     (float*)d_out, nullptr, nullptr,
                                                     BB*SS, DD, DD, 0, 0, 0, 0);
}

// Round 2
// 1069.682 us; speedup vs baseline: 1.3526x; 1.3526x over previous
//
#include <hip/hip_runtime.h>
#include <math.h>

// ---------------------------------------------------------------------------
// Problem constants (B=8, S=1024, D=1024, N=1024, C=32, K=4, H=16, dh=64)
// ---------------------------------------------------------------------------
#define BB   8
#define SS   1024
#define DD   1024
#define NN_  1024
#define HH   16
#define DH   64

typedef __bf16 bf16x8 __attribute__((ext_vector_type(8)));
typedef float  f32x4  __attribute__((ext_vector_type(4)));

#define MFMA16(a, b, c) __builtin_amdgcn_mfma_f32_16x16x32_bf16(a, b, c, 0, 0, 0)

#define GLOAD_LDS16(GP, LP)                                                  \
    __builtin_amdgcn_global_load_lds(                                        \
        (const __attribute__((address_space(1))) void*)(GP),                 \
        (__attribute__((address_space(3))) void*)(LP), 16, 0, 0)

// RNE float->bf16 and back
__device__ __forceinline__ unsigned short f2bf(float f) {
    unsigned u = __float_as_uint(f);
    u += 0x7FFFu + ((u >> 16) & 1u);
    return (unsigned short)(u >> 16);
}
__device__ __forceinline__ float bf2f(unsigned short h) {
    return __uint_as_float((unsigned)h << 16);
}
__device__ __forceinline__ void split2(float f, unsigned short& h, unsigned short& l) {
    h = f2bf(f);
    l = f2bf(f - bf2f(h));          // residual is exact in f32
}
// pack 2 f32 -> 2 bf16 in one u32 (low = a, high = b); no builtin on gfx950
__device__ __forceinline__ unsigned cvtpk_bf16(float a, float b) {
    unsigned r;
    asm("v_cvt_pk_bf16_f32 %0, %1, %2" : "=v"(r) : "v"(a), "v"(b));
    return r;
}

// LDS byte-address swizzles (involutions).
// 64B-row tiles (GEMM, BK=32 bf16): XOR bits 4-5 with bits 7-8.
__device__ __forceinline__ int swzb(int x) { return x ^ (((x >> 7) & 3) << 4); }
// 128B-row tiles (attention, 64 bf16 cols): XOR bits 4-6 with bits 7-9.
__device__ __forceinline__ int swz128(int x) { return x ^ (((x >> 7) & 7) << 4); }

// ---------------------------------------------------------------------------
// build_W -> hi/lo bf16 split output.
// out[b,n,d] = sum_k w[b,k]*inner[b,k,n]*table[idx[b,k],n,d]
// grid (N, B), block 256. Each thread: one float4 of the D=1024 row.
// ---------------------------------------------------------------------------
__global__ __launch_bounds__(256) void build_W_bf(
    const float* __restrict__ table, const int* __restrict__ idx,
    const float* __restrict__ w, const float* __restrict__ inner,
    unsigned short* __restrict__ outh, unsigned short* __restrict__ outl)
{
    const int n = blockIdx.x;
    const int b = blockIdx.y;
    const int t = threadIdx.x;

    const float c0 = w[b*4+0] * inner[((size_t)(b*4+0))*NN_ + n];
    const float c1 = w[b*4+1] * inner[((size_t)(b*4+1))*NN_ + n];
    const float c2 = w[b*4+2] * inner[((size_t)(b*4+2))*NN_ + n];
    const float c3 = w[b*4+3] * inner[((size_t)(b*4+3))*NN_ + n];

    const float4* r0 = (const float4*)(table + ((size_t)idx[b*4+0]*NN_ + n)*DD);
    const float4* r1 = (const float4*)(table + ((size_t)idx[b*4+1]*NN_ + n)*DD);
    const float4* r2 = (const float4*)(table + ((size_t)idx[b*4+2]*NN_ + n)*DD);
    const float4* r3 = (const float4*)(table + ((size_t)idx[b*4+3]*NN_ + n)*DD);

    float4 v0 = r0[t], v1 = r1[t], v2 = r2[t], v3 = r3[t];
    float4 o;
    o.x = c0*v0.x + c1*v1.x + c2*v2.x + c3*v3.x;
    o.y = c0*v0.y + c1*v1.y + c2*v2.y + c3*v3.y;
    o.z = c0*v0.z + c1*v1.z + c2*v2.z + c3*v3.z;
    o.w = c0*v0.w + c1*v1.w + c2*v2.w + c3*v3.w;

    ushort4 h, l;
    split2(o.x, h.x, l.x); split2(o.y, h.y, l.y);
    split2(o.z, h.z, l.z); split2(o.w, h.w, l.w);
    const size_t off = ((size_t)b*NN_ + n)*DD + (size_t)t*4;
    *(ushort4*)&outh[off] = h;
    *(ushort4*)&outl[off] = l;
}

// ---------------------------------------------------------------------------
// f32 -> bf16 hi/lo split, vectorized. n4 = total elements / 4.
// ---------------------------------------------------------------------------
__global__ __launch_bounds__(256) void convert_split(
    const float* __restrict__ in, unsigned short* __restrict__ oh,
    unsigned short* __restrict__ ol, int n4)
{
    const int i = blockIdx.x * 256 + threadIdx.x;
    if (i >= n4) return;
    float4 v = ((const float4*)in)[i];
    ushort4 h, l;
    split2(v.x, h.x, l.x); split2(v.y, h.y, l.y);
    split2(v.z, h.z, l.z); split2(v.w, h.w, l.w);
    ((ushort4*)oh)[i] = h;
    ((ushort4*)ol)[i] = l;
}

// ---------------------------------------------------------------------------
// Batched ushort transpose: src[b][n][d] -> dst[b][d][n]  (1024x1024 per b)
// grid (D/64, N/64, B), block 256. 64x64 tile via LDS.
// ---------------------------------------------------------------------------
__global__ __launch_bounds__(256) void transpose_u16(
    const unsigned short* __restrict__ src, unsigned short* __restrict__ dst)
{
    __shared__ __align__(16) unsigned short tile[64][72];
    const int d0 = blockIdx.x * 64;
    const int n0 = blockIdx.y * 64;
    const size_t B0 = (size_t)blockIdx.z * NN_ * DD;
    const int t = threadIdx.x;

    #pragma unroll
    for (int it = 0; it < 2; ++it) {
        const int idx = t + it * 256;          // 0..511
        const int r = idx >> 3;
        const int c = (idx & 7) * 8;
        *(uint4*)&tile[r][c] =
            *(const uint4*)&src[B0 + (size_t)(n0 + r)*DD + d0 + c];
    }
    __syncthreads();

    const int dr  = t >> 2;
    const int seg = (t & 3) * 16;
    unsigned v[8];
    #pragma unroll
    for (int u = 0; u < 8; ++u)
        v[u] = (unsigned)tile[seg + 2*u][dr] | ((unsigned)tile[seg + 2*u + 1][dr] << 16);
    uint4 a = make_uint4(v[0], v[1], v[2], v[3]);
    uint4 b = make_uint4(v[4], v[5], v[6], v[7]);
    unsigned short* drow = &dst[B0 + (size_t)(d0 + dr)*DD + n0 + seg];
    *(uint4*)&drow[0] = a;
    *(uint4*)&drow[8] = b;
}

// ---------------------------------------------------------------------------
// V transpose WITH kv-axis permutation for attention PV:
// dst[b][d][64*kt + kperm(klocal)] = src[b][64*kt + klocal][d],
// kperm(k) = 4*(k&15) + (k>>4)  (so P written as cvt_pk pairs lands k'-contig).
// grid (D/64, S/64, B), block 256.
// ---------------------------------------------------------------------------
__global__ __launch_bounds__(256) void transpose_perm_u16(
    const unsigned short* __restrict__ src, unsigned short* __restrict__ dst)
{
    __shared__ __align__(16) unsigned short tile[64][72];
    const int d0 = blockIdx.x * 64;
    const int n0 = blockIdx.y * 64;          // s-tile base (64-aligned = kv tile)
    const size_t B0 = (size_t)blockIdx.z * NN_ * DD;
    const int t = threadIdx.x;

    #pragma unroll
    for (int it = 0; it < 2; ++it) {
        const int idx = t + it * 256;
        const int r = idx >> 3;              // s-local
        const int c = (idx & 7) * 8;         // d-local
        *(uint4*)&tile[r][c] =
            *(const uint4*)&src[B0 + (size_t)(n0 + r)*DD + d0 + c];
    }
    __syncthreads();

    const int dr = t >> 2;                   // output d-row (0..63)
    const int w2 = t & 3;                    // k' chunk [16*w2, 16*w2+16)
    unsigned v32[8];
    #pragma unroll
    for (int p = 0; p < 8; ++p) {
        const int e0 = 2*p, e1 = 2*p + 1;    // e = k' - 16*w2
        const int k0 = 16*(e0 & 3) + 4*w2 + (e0 >> 2);   // inverse perm
        const int k1 = 16*(e1 & 3) + 4*w2 + (e1 >> 2);
        v32[p] = (unsigned)tile[k0][dr] | ((unsigned)tile[k1][dr] << 16);
    }
    unsigned short* drow = &dst[B0 + (size_t)(d0 + dr)*SS + n0 + 16*w2];
    *(uint4*)&drow[0] = make_uint4(v32[0], v32[1], v32[2], v32[3]);
    *(uint4*)&drow[8] = make_uint4(v32[4], v32[5], v32[6], v32[7]);
}

// ---------------------------------------------------------------------------
// bf16x3 split-precision MFMA GEMM, NT layout (verified last round).
// ---------------------------------------------------------------------------
__global__ __launch_bounds__(256) void gemm_mfma_nt(
    const unsigned short* __restrict__ Ah, const unsigned short* __restrict__ Al,
    const unsigned short* __restrict__ Bh, const unsigned short* __restrict__ Bl,
    float* __restrict__ C, unsigned short* __restrict__ Ch, unsigned short* __restrict__ Cl,
    int M, int N, int K,
    long long sA, long long sB, long long sC, int mode)
{
    __shared__ __align__(16) unsigned short sAh[4096], sAl[4096], sBh[4096], sBl[4096];

    const int bz = blockIdx.z;
    const int n0 = blockIdx.x * 128;
    const int m0 = blockIdx.y * 128;
    const int t    = threadIdx.x;
    const int lane = t & 63;
    const int w    = t >> 6;
    const int lr   = lane >> 4;
    const int lc   = lane & 15;
    const int wm   = (w >> 1) * 64;
    const int wn   = (w & 1) * 64;

    const unsigned short* gAh = Ah + (size_t)bz * sA + (size_t)m0 * K;
    const unsigned short* gAl = Al + (size_t)bz * sA + (size_t)m0 * K;
    const unsigned short* gBh = Bh + (size_t)bz * sB + (size_t)n0 * K;
    const unsigned short* gBl = Bl + (size_t)bz * sB + (size_t)n0 * K;

    int    ldsU[2];
    size_t gOff[2];
    #pragma unroll
    for (int j = 0; j < 2; ++j) {
        const int Ld = (w * 2 + j) * 1024 + lane * 16;
        const int Lg = swzb(Ld);
        ldsU[j] = ((w * 2 + j) * 1024) >> 1;
        gOff[j] = (size_t)(Lg >> 6) * K + ((Lg & 63) >> 1);
    }

    int aU[4], bU[4];
    #pragma unroll
    for (int i = 0; i < 4; ++i) {
        const int ra = wm + i * 16 + lc;
        aU[i] = swzb((ra << 6) | (lr << 4)) >> 1;
        const int rb = wn + i * 16 + lc;
        bU[i] = swzb((rb << 6) | (lr << 4)) >> 1;
    }

    f32x4 acc[4][4];
    #pragma unroll
    for (int i = 0; i < 4; ++i)
        #pragma unroll
        for (int j = 0; j < 4; ++j)
            acc[i][j] = (f32x4){0.f, 0.f, 0.f, 0.f};

    for (int k0 = 0; k0 < K; k0 += 32) {
        __syncthreads();
        #pragma unroll
        for (int j = 0; j < 2; ++j) {
            const size_t go = gOff[j] + k0;
            GLOAD_LDS16(gAh + go, &sAh[ldsU[j]]);
            GLOAD_LDS16(gAl + go, &sAl[ldsU[j]]);
            GLOAD_LDS16(gBh + go, &sBh[ldsU[j]]);
            GLOAD_LDS16(gBl + go, &sBl[ldsU[j]]);
        }
        __syncthreads();

        bf16x8 ah[4], al[4], bh[4], bl[4];
        #pragma unroll
        for (int i = 0; i < 4; ++i) {
            ah[i] = *(const bf16x8*)&sAh[aU[i]];
            al[i] = *(const bf16x8*)&sAl[aU[i]];
            bh[i] = *(const bf16x8*)&sBh[bU[i]];
            bl[i] = *(const bf16x8*)&sBl[bU[i]];
        }
        #pragma unroll
        for (int i = 0; i < 4; ++i)
            #pragma unroll
            for (int j = 0; j < 4; ++j) {
                acc[i][j] = MFMA16(ah[i], bh[j], acc[i][j]);
                acc[i][j] = MFMA16(ah[i], bl[j], acc[i][j]);
                acc[i][j] = MFMA16(al[i], bh[j], acc[i][j]);
            }
    }

    const int gr0 = m0 + wm + lr * 4;
    const int gc0 = n0 + wn + lc;
    if (mode == 0) {
        float* Cb = C + (size_t)bz * sC;
        #pragma unroll
        for (int i = 0; i < 4; ++i)
            #pragma unroll
            for (int r = 0; r < 4; ++r) {
                const size_t ro = (size_t)(gr0 + i * 16 + r) * N;
                #pragma unroll
                for (int j = 0; j < 4; ++j)
                    Cb[ro + gc0 + j * 16] = acc[i][j][r];
            }
    } else {
        unsigned short* ChB = Ch + (size_t)bz * sC;
        unsigned short* ClB = Cl + (size_t)bz * sC;
        #pragma unroll
        for (int i = 0; i < 4; ++i)
            #pragma unroll
            for (int r = 0; r < 4; ++r) {
                const size_t ro = (size_t)(gr0 + i * 16 + r) * N;
                #pragma unroll
                for (int j = 0; j < 4; ++j) {
                    unsigned short h, l;
                    split2(acc[i][j][r], h, l);
                    ChB[ro + gc0 + j * 16] = h;
                    ClB[ro + gc0 + j * 16] = l;
                }
            }
    }
}

// ---------------------------------------------------------------------------
// Causal flash attention, bf16x3 MFMA.
// Q,K: [B,S,D] hi/lo bf16; VT: [B,D,S] hi/lo bf16 with kv-perm within 64-blocks.
// Output Ab hi/lo bf16 [B,S,D].
// grid (B*H, S/128), block 256 = 4 waves; wave w owns q rows [128*qt+32w, +32).
// Per 64-kv tile: QK^T (bf16x3) -> online softmax -> P hi/lo to LDS (cvt_pk
// b64 writes, k'-permuted) -> PV (bf16x3) with VT frags in matching k' order.
// ---------------------------------------------------------------------------
__global__ __launch_bounds__(256, 2) void attn_mfma(
    const unsigned short* __restrict__ Qh, const unsigned short* __restrict__ Ql,
    const unsigned short* __restrict__ Kh, const unsigned short* __restrict__ Kl,
    const unsigned short* __restrict__ VTh, const unsigned short* __restrict__ VTl,
    unsigned short* __restrict__ Oh, unsigned short* __restrict__ Ol)
{
    __shared__ __align__(16) unsigned short sKh[4096], sKl[4096], sVh[4096], sVl[4096];
    __shared__ __align__(16) unsigned short sPh[4][2048], sPl[4][2048];

    const int bh = blockIdx.x;            // 0..127
    const int qt = blockIdx.y;            // 0..7
    const int b  = bh >> 4;
    const int h  = bh & 15;
    const int t  = threadIdx.x;
    const int lane = t & 63;
    const int w    = t >> 6;
    const int lr   = lane >> 4;
    const int lc   = lane & 15;
    const int q0 = qt * 128;
    const int wq = w * 32;

    const unsigned short* Qhb = Qh + ((size_t)b * SS) * DD + h * DH;
    const unsigned short* Qlb = Ql + ((size_t)b * SS) * DD + h * DH;
    const unsigned short* Khb = Kh + ((size_t)b * SS) * DD + h * DH;
    const unsigned short* Klb = Kl + ((size_t)b * SS) * DD + h * DH;
    const unsigned short* Vhb = VTh + ((size_t)b * DD + h * DH) * SS;
    const unsigned short* Vlb = VTl + ((size_t)b * DD + h * DH) * SS;

    // Q fragments in registers (hi/lo), loaded once.
    bf16x8 qfh[2][2], qfl[2][2];
    #pragma unroll
    for (int im = 0; im < 2; ++im)
        #pragma unroll
        for (int ks = 0; ks < 2; ++ks) {
            const size_t qo = (size_t)(q0 + wq + 16*im + lc) * DD + ks*32 + lr*8;
            qfh[im][ks] = *(const bf16x8*)(Qhb + qo);
            qfl[im][ks] = *(const bf16x8*)(Qlb + qo);
        }

    f32x4 o[2][4];
    float m_[2][4], l_[2][4];
    #pragma unroll
    for (int im = 0; im < 2; ++im)
        #pragma unroll
        for (int r = 0; r < 4; ++r) {
            m_[im][r] = -INFINITY; l_[im][r] = 0.f;
            if (r == 0) {}
        }
    #pragma unroll
    for (int im = 0; im < 2; ++im)
        #pragma unroll
        for (int j = 0; j < 4; ++j)
            o[im][j] = (f32x4){0.f, 0.f, 0.f, 0.f};

    // Staging geometry: per wave, 2KB chunk of each 8KB buffer.
    int ldsU[2], srow[2], scol[2];
    #pragma unroll
    for (int c = 0; c < 2; ++c) {
        const int Ld = w * 2048 + c * 1024 + lane * 16;
        const int Lg = swz128(Ld);
        srow[c] = Lg >> 7;
        scol[c] = (Lg & 127) >> 1;
        ldsU[c] = (w * 2048 + c * 1024) >> 1;
    }

    const int ktmax = 2 * qt + 1;
    for (int kt = 0; kt <= ktmax; ++kt) {
        const int kv0 = kt * 64;
        __syncthreads();                   // prev tile frag reads done
        #pragma unroll
        for (int c = 0; c < 2; ++c) {
            GLOAD_LDS16(Khb + (size_t)(kv0 + srow[c]) * DD + scol[c], &sKh[ldsU[c]]);
            GLOAD_LDS16(Klb + (size_t)(kv0 + srow[c]) * DD + scol[c], &sKl[ldsU[c]]);
            GLOAD_LDS16(Vhb + (size_t)srow[c] * SS + kv0 + scol[c], &sVh[ldsU[c]]);
            GLOAD_LDS16(Vlb + (size_t)srow[c] * SS + kv0 + scol[c], &sVl[ldsU[c]]);
        }
        __syncthreads();                   // staging landed

        // ---- S = Q K^T (bf16x3) ----
        f32x4 s[2][4];
        #pragma unroll
        for (int im = 0; im < 2; ++im)
            #pragma unroll
            for (int j = 0; j < 4; ++j)
                s[im][j] = (f32x4){0.f, 0.f, 0.f, 0.f};

        #pragma unroll
        for (int ks = 0; ks < 2; ++ks)
            #pragma unroll
            for (int j = 0; j < 4; ++j) {
                const int kb = swz128(((16*j + lc) << 7) + ks*64 + lr*16) >> 1;
                bf16x8 kh = *(const bf16x8*)&sKh[kb];
                bf16x8 kl = *(const bf16x8*)&sKl[kb];
                #pragma unroll
                for (int im = 0; im < 2; ++im) {
                    s[im][j] = MFMA16(qfh[im][ks], kh, s[im][j]);
                    s[im][j] = MFMA16(qfh[im][ks], kl, s[im][j]);
                    s[im][j] = MFMA16(qfl[im][ks], kh, s[im][j]);
                }
            }

        // ---- causal mask + online softmax (rows = 16im + 4lr + r) ----
        const bool masked = (kv0 + 63 > q0 + wq);
        #pragma unroll
        for (int im = 0; im < 2; ++im)
            #pragma unroll
            for (int r = 0; r < 4; ++r) {
                const int qrow = q0 + wq + 16*im + 4*lr + r;
                float v0 = s[im][0][r] * 0.125f;
                float v1 = s[im][1][r] * 0.125f;
                float v2 = s[im][2][r] * 0.125f;
                float v3 = s[im][3][r] * 0.125f;
                if (masked) {
                    if (kv0 +  0 + lc > qrow) v0 = -INFINITY;
                    if (kv0 + 16 + lc > qrow) v1 = -INFINITY;
                    if (kv0 + 32 + lc > qrow) v2 = -INFINITY;
                    if (kv0 + 48 + lc > qrow) v3 = -INFINITY;
                }
                float pm = fmaxf(fmaxf(v0, v1), fmaxf(v2, v3));
                #pragma unroll
                for (int off = 1; off <= 8; off <<= 1)
                    pm = fmaxf(pm, __shfl_xor(pm, off, 64));
                const float mn = fmaxf(m_[im][r], pm);
                const float alpha = __expf(m_[im][r] - mn);
                float p0 = __expf(v0 - mn);
                float p1 = __expf(v1 - mn);
                float p2 = __expf(v2 - mn);
                float p3 = __expf(v3 - mn);
                float rs = p0 + p1 + p2 + p3;
                #pragma unroll
                for (int off = 1; off <= 8; off <<= 1)
                    rs += __shfl_xor(rs, off, 64);
                l_[im][r] = l_[im][r] * alpha + rs;
                m_[im][r] = mn;
                o[im][0][r] *= alpha; o[im][1][r] *= alpha;
                o[im][2][r] *= alpha; o[im][3][r] *= alpha;
                s[im][0][r] = p0; s[im][1][r] = p1;
                s[im][2][r] = p2; s[im][3][r] = p3;
            }

        // ---- write P hi/lo to per-wave LDS, k' = 4*lc + j (permuted) ----
        #pragma unroll
        for (int im = 0; im < 2; ++im)
            #pragma unroll
            for (int r = 0; r < 4; ++r) {
                const int m  = 16*im + 4*lr + r;
                const int bo = (m * 128 + lc * 8) ^ ((m & 7) << 4);
                const unsigned hA = cvtpk_bf16(s[im][0][r], s[im][1][r]);
                const unsigned hB = cvtpk_bf16(s[im][2][r], s[im][3][r]);
                *(uint2*)((char*)&sPh[w][0] + bo) = make_uint2(hA, hB);
                const float r0 = s[im][0][r] - __uint_as_float(hA << 16);
                const float r1 = s[im][1][r] - __uint_as_float(hA & 0xffff0000u);
                const float r2 = s[im][2][r] - __uint_as_float(hB << 16);
                const float r3 = s[im][3][r] - __uint_as_float(hB & 0xffff0000u);
                *(uint2*)((char*)&sPl[w][0] + bo) =
                    make_uint2(cvtpk_bf16(r0, r1), cvtpk_bf16(r2, r3));
            }

        // ---- O += P V (bf16x3), contraction in k' order on both operands ----
        #pragma unroll
        for (int ks = 0; ks < 2; ++ks) {
            bf16x8 pah[2], pal[2];
            #pragma unroll
            for (int im = 0; im < 2; ++im) {
                const int ab = swz128(((16*im + lc) << 7) + ks*64 + lr*16) >> 1;
                pah[im] = *(const bf16x8*)&sPh[w][ab];
                pal[im] = *(const bf16x8*)&sPl[w][ab];
            }
            #pragma unroll
            for (int jd = 0; jd < 4; ++jd) {
                const int bb = swz128(((16*jd + lc) << 7) + ks*64 + lr*16) >> 1;
                bf16x8 vh = *(const bf16x8*)&sVh[bb];
                bf16x8 vl = *(const bf16x8*)&sVl[bb];
                #pragma unroll
                for (int im = 0; im < 2; ++im) {
                    o[im][jd] = MFMA16(pah[im], vh, o[im][jd]);
                    o[im][jd] = MFMA16(pah[im], vl, o[im][jd]);
                    o[im][jd] = MFMA16(pal[im], vh, o[im][jd]);
                }
            }
        }
    }

    // ---- epilogue: normalize, split hi/lo, store ----
    #pragma unroll
    for (int im = 0; im < 2; ++im)
        #pragma unroll
        for (int r = 0; r < 4; ++r) {
            const float inv = 1.f / l_[im][r];
            const int qrow = q0 + wq + 16*im + 4*lr + r;
            const size_t rowo = ((size_t)b * SS + qrow) * DD + h * DH + lc;
            #pragma unroll
            for (int jd = 0; jd < 4; ++jd) {
                const float v = o[im][jd][r] * inv;
                unsigned short hh, ll;
                split2(v, hh, ll);
                Oh[rowo + 16*jd] = hh;
                Ol[rowo + 16*jd] = ll;
            }
        }
}

// ---------------------------------------------------------------------------
// Launch. Workspace: 6 x 32MB = 192MB, recycled:
//  buf0: W hi/lo (all builds)         -> Ab hi/lo (attn out)
//  buf1: W^T hi/lo                    -> W_O hi/lo
//  buf2: x hi/lo                      -> Q hi/lo
//  buf3: h_r hi/lo                    -> V hi/lo
//  buf4: h_v hi/lo                    -> VT hi/lo (permuted)
//  buf5: K hi/lo
// ---------------------------------------------------------------------------
extern "C" void kernel_launch(void* const* d_in, const int* in_sizes, int n_in,
                              void* d_out, int out_size, void* d_ws, size_t ws_size,
                              hipStream_t stream)
{
    const float* x      = (const float*)d_in[0];
    const float* feat_r = (const float*)d_in[1];
    const float* feat_v = (const float*)d_in[2];
    const float* rel    = (const float*)d_in[3];
    const float* val    = (const float*)d_in[4];
    const float* W_O    = (const float*)d_in[5];
    const int*   idx_r  = (const int*)d_in[6];
    const float* w_r    = (const float*)d_in[7];
    const float* in_r   = (const float*)d_in[8];
    const int*   idx_v  = (const int*)d_in[9];
    const float* w_v    = (const float*)d_in[10];
    const float* in_v   = (const float*)d_in[11];
    const int*   idx_q  = (const int*)d_in[12];
    const float* w_q    = (const float*)d_in[13];
    const float* in_q   = (const float*)d_in[14];
    const int*   idx_k  = (const int*)d_in[15];
    const float* w_k    = (const float*)d_in[16];
    const float* in_k   = (const float*)d_in[17];
    const int*   idx_va = (const int*)d_in[18];
    const float* w_va   = (const float*)d_in[19];
    const float* in_va  = (const float*)d_in[20];

    char* base = (char*)d_ws;
    const size_t BUFB = (size_t)32 * 1024 * 1024;
    const size_t HM   = (size_t)8 * 1024 * 1024;     // ushorts per half-buffer

    unsigned short* Wh  = (unsigned short*)(base + 0*BUFB);
    unsigned short* Wl  = Wh + HM;
    unsigned short* Abh = Wh;
    unsigned short* Abl = Wl;
    unsigned short* Th  = (unsigned short*)(base + 1*BUFB);
    unsigned short* Tl  = Th + HM;
    unsigned short* Woh = Th;
    unsigned short* Wol = Tl;
    unsigned short* Xh  = (unsigned short*)(base + 2*BUFB);
    unsigned short* Xl  = Xh + HM;
    unsigned short* Qbh = Xh;                        // after x dead
    unsigned short* Qbl = Xl;
    unsigned short* Hrh = (unsigned short*)(base + 3*BUFB);
    unsigned short* Hrl = Hrh + HM;
    unsigned short* Vh  = Hrh;                       // after h_r dead
    unsigned short* Vl  = Hrl;
    unsigned short* Hvh = (unsigned short*)(base + 4*BUFB);
    unsigned short* Hvl = Hvh + HM;
    unsigned short* VTh = Hvh;                       // after h_v dead
    unsigned short* VTl = Hvl;
    unsigned short* Kbh = (unsigned short*)(base + 5*BUFB);
    unsigned short* Kbl = Kbh + HM;

    const dim3 blk(256);
    const dim3 gBuild(NN_, BB);
    const dim3 gGemmB(8, 8, BB);
    const dim3 gTr(16, 16, BB);
    const long long sM = (long long)SS * DD;

    // x -> hi/lo
    convert_split<<<8192, blk, 0, stream>>>(x, Xh, Xl, 2*1024*1024);

    // h_r = x @ W_r^T   (hi/lo out)
    build_W_bf<<<gBuild, blk, 0, stream>>>(feat_r, idx_r, w_r, in_r, Wh, Wl);
    gemm_mfma_nt<<<gGemmB, blk, 0, stream>>>(Xh, Xl, Wh, Wl, nullptr, Hrh, Hrl,
                                             SS, NN_, DD, sM, sM, sM, 1);
    // h_v = x @ W_v^T
    build_W_bf<<<gBuild, blk, 0, stream>>>(feat_v, idx_v, w_v, in_v, Wh, Wl);
    gemm_mfma_nt<<<gGemmB, blk, 0, stream>>>(Xh, Xl, Wh, Wl, nullptr, Hvh, Hvl,
                                             SS, NN_, DD, sM, sM, sM, 1);
    // Q = h_r @ W_rel_Q  (hi/lo out into old x buffer)
    build_W_bf<<<gBuild, blk, 0, stream>>>(rel, idx_q, w_q, in_q, Wh, Wl);
    transpose_u16<<<gTr, blk, 0, stream>>>(Wh, Th);
    transpose_u16<<<gTr, blk, 0, stream>>>(Wl, Tl);
    gemm_mfma_nt<<<gGemmB, blk, 0, stream>>>(Hrh, Hrl, Th, Tl, nullptr, Qbh, Qbl,
                                             SS, DD, NN_, sM, sM, sM, 1);
    // K = h_r @ W_rel_K
    build_W_bf<<<gBuild, blk, 0, stream>>>(rel, idx_k, w_k, in_k, Wh, Wl);
    transpose_u16<<<gTr, blk, 0, stream>>>(Wh, Th);
    transpose_u16<<<gTr, blk, 0, stream>>>(Wl, Tl);
    gemm_mfma_nt<<<gGemmB, blk, 0, stream>>>(Hrh, Hrl, Th, Tl, nullptr, Kbh, Kbl,
                                             SS, DD, NN_, sM, sM, sM, 1);
    // V = h_v @ W_val  (into old h_r buffer)
    build_W_bf<<<gBuild, blk, 0, stream>>>(val, idx_va, w_va, in_va, Wh, Wl);
    transpose_u16<<<gTr, blk, 0, stream>>>(Wh, Th);
    transpose_u16<<<gTr, blk, 0, stream>>>(Wl, Tl);
    gemm_mfma_nt<<<gGemmB, blk, 0, stream>>>(Hvh, Hvl, Th, Tl, nullptr, Vh, Vl,
                                             SS, DD, NN_, sM, sM, sM, 1);
    // V^T (kv-permuted) into old h_v buffer
    transpose_perm_u16<<<gTr, blk, 0, stream>>>(Vh, VTh);
    transpose_perm_u16<<<gTr, blk, 0, stream>>>(Vl, VTl);

    // attention (bf16x3 MFMA) -> Ab hi/lo (old W buffer)
    attn_mfma<<<dim3(BB*HH, SS/128), blk, 0, stream>>>(Qbh, Qbl, Kbh, Kbl,
                                                       VTh, VTl, Abh, Abl);

    // out = Ab @ W_O^T  (M = 8192, single batch, f32 out)
    convert_split<<<1024, blk, 0, stream>>>(W_O, Woh, Wol, 256*1024);
    gemm_mfma_nt<<<dim3(8, 64, 1), blk, 0, stream>>>(Abh, Abl, Woh, Wol,
                                                     (float*)d_out, nullptr, nullptr,
                                                     BB*SS, DD, DD, 0, 0, 0, 0);
}